// Round 11
// baseline (180.156 us; speedup 1.0000x reference)
//
#include <hip/hip_runtime.h>

#define NNODE 50000
#define NEDGE 800000
#define NBUCKET 196         // ceil(50000 / 256), bucket = dst >> 8
#define NPB 256             // nodes per bucket
#define EPB 3125            // NEDGE / 256 edges per producer block

// ---------------- Pass A: deterministic-base bucketize (bucket = dst>>8) ----

__global__ __launch_bounds__(256) void k_histA(const int* __restrict__ dst, int* __restrict__ hist_g) {
    __shared__ int h[NBUCKET];
    const int tid = threadIdx.x, pb = blockIdx.x, e0 = pb * EPB;
    if (tid < NBUCKET) h[tid] = 0;
    __syncthreads();
    for (int i = tid; i < EPB; i += 256)
        atomicAdd(&h[dst[e0 + i] >> 8], 1);
    __syncthreads();
    if (tid < NBUCKET) hist_g[tid * 256 + pb] = h[tid];
}

__global__ __launch_bounds__(256) void k_scanA1(const int* __restrict__ hist_g, int* __restrict__ base_g,
                                                int* __restrict__ colsum) {
    __shared__ int s[256];
    const int b = blockIdx.x, t = threadIdx.x;
    int v = hist_g[b * 256 + t];
    s[t] = v;
    __syncthreads();
#pragma unroll
    for (int off = 1; off < 256; off <<= 1) {
        int a = (t >= off) ? s[t - off] : 0;
        __syncthreads();
        s[t] += a;
        __syncthreads();
    }
    base_g[b * 256 + t] = s[t] - v;           // exclusive
    if (t == 255) colsum[b] = s[t];
}

__global__ __launch_bounds__(256) void k_scanA2(const int* __restrict__ colsum, int* __restrict__ bucketbase,
                                                int* __restrict__ rowstart) {
    __shared__ int s[256];
    const int t = threadIdx.x;
    int v = (t < NBUCKET) ? colsum[t] : 0;
    s[t] = v;
    __syncthreads();
#pragma unroll
    for (int off = 1; off < 256; off <<= 1) {
        int a = (t >= off) ? s[t - off] : 0;
        __syncthreads();
        s[t] += a;
        __syncthreads();
    }
    if (t < NBUCKET) bucketbase[t] = s[t] - v;
    if (t == 0) { bucketbase[NBUCKET] = NEDGE; rowstart[NNODE] = NEDGE; }
}

__global__ __launch_bounds__(256) void k_scatterA(const int* __restrict__ src, const int* __restrict__ dst,
                          const int* __restrict__ base_g, const int* __restrict__ bucketbase,
                          unsigned int* __restrict__ bucketed) {
    __shared__ int cur[NBUCKET];
    const int tid = threadIdx.x, pb = blockIdx.x, e0 = pb * EPB;
    if (tid < NBUCKET) cur[tid] = bucketbase[tid] + base_g[tid * 256 + pb];
    __syncthreads();
    for (int i = tid; i < EPB; i += 256) {
        int d = dst[e0 + i], s = src[e0 + i];
        int pos = atomicAdd(&cur[d >> 8], 1);
        bucketed[pos] = ((unsigned int)d << 16) | (unsigned int)s;
    }
}

// ---------------- Pass B: per-bucket fine CSR (contiguous reads) ----------

__global__ __launch_bounds__(256) void k_bucketB2(const unsigned int* __restrict__ bucketed,
                          const int* __restrict__ bucketbase, int* __restrict__ rowstart,
                          int* __restrict__ csr_src, float* __restrict__ dinv) {
    __shared__ int cnt[NPB];
    __shared__ int ex[NPB];
    __shared__ int cur[NPB];
    const int tid = threadIdx.x, b = blockIdx.x;
    const int base_out = bucketbase[b], end_out = bucketbase[b + 1];

    cnt[tid] = 0;
    __syncthreads();
    for (int i = base_out + tid; i < end_out; i += 256)
        atomicAdd(&cnt[(bucketed[i] >> 16) & 255], 1);
    __syncthreads();

    int v = cnt[tid];
    ex[tid] = v;
    __syncthreads();
#pragma unroll
    for (int off = 1; off < 256; off <<= 1) {
        int a = (tid >= off) ? ex[tid - off] : 0;
        __syncthreads();
        ex[tid] += a;
        __syncthreads();
    }
    int excl = ex[tid] - v;
    int node = (b << 8) + tid;
    cur[tid] = base_out + excl;
    if (node < NNODE) {
        rowstart[node] = base_out + excl;
        dinv[node] = rsqrtf((float)v + 1.0f);
    }
    __syncthreads();

    for (int i = base_out + tid; i < end_out; i += 256) {
        unsigned int u = bucketed[i];
        int pos = atomicAdd(&cur[(u >> 16) & 255], 1);
        csr_src[pos] = (int)(u & 0xFFFFu);
    }
}

// ---------------- GEMM + prescale: 64x64 LDS tile (unchanged R7) ----------------

template<int FIN, int FOUT>
__launch_bounds__(256)
__global__ void k_gemm_prescale(const float* __restrict__ X, const float* __restrict__ W,
                                const float* __restrict__ dinv, float* __restrict__ XWs) {
    __shared__ float Xt[FIN * 68];
    __shared__ float Ws[FIN * 64];

    const int tid = threadIdx.x;
    const int r0 = blockIdx.x * 64;

    for (int idx = tid; idx < FIN * 64; idx += 256) {
        int k = idx >> 6, c = idx & 63;
        Ws[idx] = (c < FOUT) ? W[k * FOUT + c] : 0.0f;
    }

    constexpr int CH = FIN / 4;
    constexpr int CSH = (FIN == 128) ? 5 : 4;
    for (int idx = tid; idx < 64 * CH; idx += 256) {
        int r_lo = idx & 7;
        int c = (idx >> 3) & (CH - 1);
        int r = ((idx >> (3 + CSH)) << 3) + r_lo;
        int rr = r0 + r; if (rr >= NNODE) rr = NNODE - 1;   // clamp tail block
        float4 v = *(const float4*)(X + (size_t)rr * FIN + c * 4);
        Xt[(4 * c + 0) * 68 + r] = v.x;
        Xt[(4 * c + 1) * 68 + r] = v.y;
        Xt[(4 * c + 2) * 68 + r] = v.z;
        Xt[(4 * c + 3) * 68 + r] = v.w;
    }
    __syncthreads();

    const int cg = tid & 15;    // col group
    const int rg = tid >> 4;    // row group

    float acc[4][4] = {};
#pragma unroll 4
    for (int k = 0; k < FIN; ++k) {
        float4 xv = *(const float4*)&Xt[k * 68 + 4 * rg];
        float4 wv = *(const float4*)&Ws[k * 64 + 4 * cg];
#pragma unroll
        for (int i = 0; i < 4; ++i) {
            float xi = (i == 0) ? xv.x : (i == 1) ? xv.y : (i == 2) ? xv.z : xv.w;
            acc[i][0] = fmaf(xi, wv.x, acc[i][0]);
            acc[i][1] = fmaf(xi, wv.y, acc[i][1]);
            acc[i][2] = fmaf(xi, wv.z, acc[i][2]);
            acc[i][3] = fmaf(xi, wv.w, acc[i][3]);
        }
    }

    if (4 * cg + 4 <= FOUT) {
#pragma unroll
        for (int i = 0; i < 4; ++i) {
            int row = r0 + 4 * rg + i;
            if (row < NNODE) {
                float dv = dinv[row];
                float4 o = { acc[i][0] * dv, acc[i][1] * dv, acc[i][2] * dv, acc[i][3] * dv };
                *(float4*)(XWs + (size_t)row * FOUT + 4 * cg) = o;
            }
        }
    }
}

// ---------------- CSR aggregate + finalize: 4-edge float4 groups ----------
// wave per node; lane = g*16+q (g = edge group, q = float4 feature slot).
// One load instruction gathers 4 edges x 256B = 1KB. Cross-group reduce via
// __shfl_xor(16|32); group 0 adds self-loop, bias, scales, stores.

template<int F, bool RELU>
__launch_bounds__(256)
__global__ void k_aggregate(const float* __restrict__ XWs, const int* __restrict__ rowstart,
                            const int* __restrict__ csr_src, const float* __restrict__ dinv,
                            const float* __restrict__ b, float* __restrict__ out) {
    constexpr int NF4 = F / 4;          // 16 for F=64, 10 for F=40
    const int wid  = threadIdx.x >> 6;
    const int lane = threadIdx.x & 63;
    const int g = lane >> 4;            // edge group 0..3
    const int q = lane & 15;            // float4 slot
    const int d = blockIdx.x * 4 + wid;
    if (d >= NNODE) return;

    const int beg = rowstart[d];
    const int end = rowstart[d + 1];
    const bool qa = (q < NF4);

    float4 acc = {0.f, 0.f, 0.f, 0.f};

    for (int base = beg; base < end; base += 64) {
        int idx = base + lane;
        int sv = (idx < end) ? csr_src[idx] : 0;   // coalesced edge-list load
        int nv = min(64, end - base);
        for (int j = 0; j < nv; j += 4) {
            int jj = j + g;
            int s = __shfl(sv, jj);                // per-lane index -> bpermute
            if (jj < nv && qa) {
                float4 v = *(const float4*)(XWs + (size_t)s * F + 4 * q);
                acc.x += v.x; acc.y += v.y; acc.z += v.z; acc.w += v.w;
            }
        }
    }

    // reduce the 4 groups (lane bits 4,5)
#pragma unroll
    for (int mask = 16; mask <= 32; mask <<= 1) {
        acc.x += __shfl_xor(acc.x, mask);
        acc.y += __shfl_xor(acc.y, mask);
        acc.z += __shfl_xor(acc.z, mask);
        acc.w += __shfl_xor(acc.w, mask);
    }

    if (g == 0 && qa) {
        float4 self = *(const float4*)(XWs + (size_t)d * F + 4 * q);
        float4 bb   = *(const float4*)(b + 4 * q);
        float dv = dinv[d];
        float4 o;
        o.x = fmaf(acc.x + self.x, dv, bb.x);
        o.y = fmaf(acc.y + self.y, dv, bb.y);
        o.z = fmaf(acc.z + self.z, dv, bb.z);
        o.w = fmaf(acc.w + self.w, dv, bb.w);
        if (RELU) {
            o.x = fmaxf(o.x, 0.f); o.y = fmaxf(o.y, 0.f);
            o.z = fmaxf(o.z, 0.f); o.w = fmaxf(o.w, 0.f);
        }
        *(float4*)(out + (size_t)d * F + 4 * q) = o;
    }
}

extern "C" void kernel_launch(void* const* d_in, const int* in_sizes, int n_in,
                              void* d_out, int out_size, void* d_ws, size_t ws_size,
                              hipStream_t stream) {
    const float* x  = (const float*)d_in[0];
    const int*   ei = (const int*)d_in[1];
    const float* W1 = (const float*)d_in[2];
    const float* b1 = (const float*)d_in[3];
    const float* W2 = (const float*)d_in[4];
    const float* b2 = (const float*)d_in[5];
    const float* W3 = (const float*)d_in[6];
    const float* b3 = (const float*)d_in[7];
    float* out = (float*)d_out;

    const int* src = ei;
    const int* dst = ei + NEDGE;

    char* p = (char*)d_ws;
    auto alloc = [&](size_t bytes) { char* r = p; p += (bytes + 255) & ~size_t(255); return r; };
    unsigned int* bucketed = (unsigned int*)alloc((size_t)NEDGE * 4);
    int*   hist_g     = (int*)  alloc(NBUCKET * 256 * 4);
    int*   base_g     = (int*)  alloc(NBUCKET * 256 * 4);
    int*   colsum     = (int*)  alloc(NBUCKET * 4);
    int*   bucketbase = (int*)  alloc((NBUCKET + 1) * 4);
    int*   rowstart   = (int*)  alloc((NNODE + 1) * 4);
    int*   csr_src    = (int*)  alloc((size_t)NEDGE * 4);
    float* dinv       = (float*)alloc(NNODE * 4);
    float* XWs        = (float*)alloc((size_t)NNODE * 64 * 4 + 256);
    float* H1         = (float*)alloc((size_t)NNODE * 64 * 4);
    float* H2         = (float*)alloc((size_t)NNODE * 64 * 4);

    const int B = 256;
    const int gGemm = (NNODE + 63) / 64;          // 782 (64 rows/block)
    const int gAgg  = (NNODE + 3) / 4;            // 12500

    // CSR build + norm (deterministic-base counting sort)
    k_histA   <<<256, B, 0, stream>>>(dst, hist_g);
    k_scanA1  <<<NBUCKET, B, 0, stream>>>(hist_g, base_g, colsum);
    k_scanA2  <<<1, B, 0, stream>>>(colsum, bucketbase, rowstart);
    k_scatterA<<<256, B, 0, stream>>>(src, dst, base_g, bucketbase, bucketed);
    k_bucketB2<<<NBUCKET, B, 0, stream>>>(bucketed, bucketbase, rowstart, csr_src, dinv);

    // layer 1: 128 -> 64, relu
    k_gemm_prescale<128, 64><<<gGemm, B, 0, stream>>>(x, W1, dinv, XWs);
    k_aggregate<64, true><<<gAgg, B, 0, stream>>>(XWs, rowstart, csr_src, dinv, b1, H1);

    // layer 2: 64 -> 64, relu
    k_gemm_prescale<64, 64><<<gGemm, B, 0, stream>>>(H1, W2, dinv, XWs);
    k_aggregate<64, true><<<gAgg, B, 0, stream>>>(XWs, rowstart, csr_src, dinv, b2, H2);

    // layer 3: 64 -> 40, no act
    k_gemm_prescale<64, 40><<<gGemm, B, 0, stream>>>(H2, W3, dinv, XWs);
    k_aggregate<40, false><<<gAgg, B, 0, stream>>>(XWs, rowstart, csr_src, dinv, b3, out);
}

// Round 12
// 159.808 us; speedup vs baseline: 1.1273x; 1.1273x over previous
//
#include <hip/hip_runtime.h>

#define NNODE 50000
#define NEDGE 800000
#define NBUCKET 196         // ceil(50000 / 256), bucket = dst >> 8
#define NPB 256             // nodes per bucket
#define EPB 3125            // NEDGE / 256 edges per producer block

typedef __attribute__((ext_vector_type(8))) unsigned short ushort8v;

__device__ inline unsigned short f2bf(float f) {           // round-to-nearest-even
    unsigned int u = __float_as_uint(f);
    u += 0x7FFFu + ((u >> 16) & 1u);
    return (unsigned short)(u >> 16);
}
__device__ inline float bf2f(unsigned short h) {
    return __uint_as_float((unsigned int)h << 16);
}

// ---------------- Pass A: deterministic-base bucketize (bucket = dst>>8) ----

__global__ __launch_bounds__(256) void k_histA(const int* __restrict__ dst, int* __restrict__ hist_g) {
    __shared__ int h[NBUCKET];
    const int tid = threadIdx.x, pb = blockIdx.x, e0 = pb * EPB;
    if (tid < NBUCKET) h[tid] = 0;
    __syncthreads();
    for (int i = tid; i < EPB; i += 256)
        atomicAdd(&h[dst[e0 + i] >> 8], 1);
    __syncthreads();
    if (tid < NBUCKET) hist_g[tid * 256 + pb] = h[tid];
}

__global__ __launch_bounds__(256) void k_scanA1(const int* __restrict__ hist_g, int* __restrict__ base_g,
                                                int* __restrict__ colsum) {
    __shared__ int s[256];
    const int b = blockIdx.x, t = threadIdx.x;
    int v = hist_g[b * 256 + t];
    s[t] = v;
    __syncthreads();
#pragma unroll
    for (int off = 1; off < 256; off <<= 1) {
        int a = (t >= off) ? s[t - off] : 0;
        __syncthreads();
        s[t] += a;
        __syncthreads();
    }
    base_g[b * 256 + t] = s[t] - v;           // exclusive
    if (t == 255) colsum[b] = s[t];
}

__global__ __launch_bounds__(256) void k_scanA2(const int* __restrict__ colsum, int* __restrict__ bucketbase,
                                                int* __restrict__ rowstart) {
    __shared__ int s[256];
    const int t = threadIdx.x;
    int v = (t < NBUCKET) ? colsum[t] : 0;
    s[t] = v;
    __syncthreads();
#pragma unroll
    for (int off = 1; off < 256; off <<= 1) {
        int a = (t >= off) ? s[t - off] : 0;
        __syncthreads();
        s[t] += a;
        __syncthreads();
    }
    if (t < NBUCKET) bucketbase[t] = s[t] - v;
    if (t == 0) { bucketbase[NBUCKET] = NEDGE; rowstart[NNODE] = NEDGE; }
}

__global__ __launch_bounds__(256) void k_scatterA(const int* __restrict__ src, const int* __restrict__ dst,
                          const int* __restrict__ base_g, const int* __restrict__ bucketbase,
                          unsigned int* __restrict__ bucketed) {
    __shared__ int cur[NBUCKET];
    const int tid = threadIdx.x, pb = blockIdx.x, e0 = pb * EPB;
    if (tid < NBUCKET) cur[tid] = bucketbase[tid] + base_g[tid * 256 + pb];
    __syncthreads();
    for (int i = tid; i < EPB; i += 256) {
        int d = dst[e0 + i], s = src[e0 + i];
        int pos = atomicAdd(&cur[d >> 8], 1);
        bucketed[pos] = ((unsigned int)d << 16) | (unsigned int)s;
    }
}

// ---------------- Pass B: per-bucket fine CSR (contiguous reads) ----------

__global__ __launch_bounds__(256) void k_bucketB2(const unsigned int* __restrict__ bucketed,
                          const int* __restrict__ bucketbase, int* __restrict__ rowstart,
                          int* __restrict__ csr_src, float* __restrict__ dinv) {
    __shared__ int cnt[NPB];
    __shared__ int ex[NPB];
    __shared__ int cur[NPB];
    const int tid = threadIdx.x, b = blockIdx.x;
    const int base_out = bucketbase[b], end_out = bucketbase[b + 1];

    cnt[tid] = 0;
    __syncthreads();
    for (int i = base_out + tid; i < end_out; i += 256)
        atomicAdd(&cnt[(bucketed[i] >> 16) & 255], 1);
    __syncthreads();

    int v = cnt[tid];
    ex[tid] = v;
    __syncthreads();
#pragma unroll
    for (int off = 1; off < 256; off <<= 1) {
        int a = (tid >= off) ? ex[tid - off] : 0;
        __syncthreads();
        ex[tid] += a;
        __syncthreads();
    }
    int excl = ex[tid] - v;
    int node = (b << 8) + tid;
    cur[tid] = base_out + excl;
    if (node < NNODE) {
        rowstart[node] = base_out + excl;
        dinv[node] = rsqrtf((float)v + 1.0f);
    }
    __syncthreads();

    for (int i = base_out + tid; i < end_out; i += 256) {
        unsigned int u = bucketed[i];
        int pos = atomicAdd(&cur[(u >> 16) & 255], 1);
        csr_src[pos] = (int)(u & 0xFFFFu);
    }
}

// ---------------- GEMM + prescale: 64x64 LDS tile, bf16 output ----------------

template<int FIN, int FOUT>
__launch_bounds__(256)
__global__ void k_gemm_prescale(const float* __restrict__ X, const float* __restrict__ W,
                                const float* __restrict__ dinv, unsigned short* __restrict__ XWs) {
    __shared__ float Xt[FIN * 68];
    __shared__ float Ws[FIN * 64];

    const int tid = threadIdx.x;
    const int r0 = blockIdx.x * 64;

    for (int idx = tid; idx < FIN * 64; idx += 256) {
        int k = idx >> 6, c = idx & 63;
        Ws[idx] = (c < FOUT) ? W[k * FOUT + c] : 0.0f;
    }

    constexpr int CH = FIN / 4;
    constexpr int CSH = (FIN == 128) ? 5 : 4;
    for (int idx = tid; idx < 64 * CH; idx += 256) {
        int r_lo = idx & 7;
        int c = (idx >> 3) & (CH - 1);
        int r = ((idx >> (3 + CSH)) << 3) + r_lo;
        int rr = r0 + r; if (rr >= NNODE) rr = NNODE - 1;   // clamp tail block
        float4 v = *(const float4*)(X + (size_t)rr * FIN + c * 4);
        Xt[(4 * c + 0) * 68 + r] = v.x;
        Xt[(4 * c + 1) * 68 + r] = v.y;
        Xt[(4 * c + 2) * 68 + r] = v.z;
        Xt[(4 * c + 3) * 68 + r] = v.w;
    }
    __syncthreads();

    const int cg = tid & 15;    // col group
    const int rg = tid >> 4;    // row group

    float acc[4][4] = {};
#pragma unroll 4
    for (int k = 0; k < FIN; ++k) {
        float4 xv = *(const float4*)&Xt[k * 68 + 4 * rg];
        float4 wv = *(const float4*)&Ws[k * 64 + 4 * cg];
#pragma unroll
        for (int i = 0; i < 4; ++i) {
            float xi = (i == 0) ? xv.x : (i == 1) ? xv.y : (i == 2) ? xv.z : xv.w;
            acc[i][0] = fmaf(xi, wv.x, acc[i][0]);
            acc[i][1] = fmaf(xi, wv.y, acc[i][1]);
            acc[i][2] = fmaf(xi, wv.z, acc[i][2]);
            acc[i][3] = fmaf(xi, wv.w, acc[i][3]);
        }
    }

    if (4 * cg + 4 <= FOUT) {
#pragma unroll
        for (int i = 0; i < 4; ++i) {
            int row = r0 + 4 * rg + i;
            if (row < NNODE) {
                float dv = dinv[row];
                ushort4 o = { f2bf(acc[i][0] * dv), f2bf(acc[i][1] * dv),
                              f2bf(acc[i][2] * dv), f2bf(acc[i][3] * dv) };
                *(ushort4*)(XWs + (size_t)row * FOUT + 4 * cg) = o;
            }
        }
    }
}

// ---------------- CSR aggregate + finalize: 8-edge bf16 ushort8 groups -----
// wave per node; lane = g*8+q (g = edge group 0..7, q = feature octet).
// One load instruction gathers 8 rows x 128B = 1KB (F=64). f32 accumulate.

template<int F, bool RELU>
__launch_bounds__(256)
__global__ void k_aggregate(const unsigned short* __restrict__ XWs, const int* __restrict__ rowstart,
                            const int* __restrict__ csr_src, const float* __restrict__ dinv,
                            const float* __restrict__ b, float* __restrict__ out) {
    constexpr int NQ = F / 8;           // 8 for F=64, 5 for F=40
    const int wid  = threadIdx.x >> 6;
    const int lane = threadIdx.x & 63;
    const int g = lane >> 3;            // edge group 0..7
    const int q = lane & 7;             // feature octet
    const int d = blockIdx.x * 4 + wid;
    if (d >= NNODE) return;

    const int beg = rowstart[d];
    const int end = rowstart[d + 1];
    const bool qa = (q < NQ);

    float acc[8] = {};

    for (int base = beg; base < end; base += 64) {
        int idx = base + lane;
        int sv = (idx < end) ? csr_src[idx] : 0;   // coalesced edge-list load
        int nv = min(64, end - base);
        for (int j = 0; j < nv; j += 8) {
            int jj = j + g;
            int s = __shfl(sv, jj);
            if (jj < nv && qa) {
                ushort8v v = *(const ushort8v*)(XWs + (size_t)s * F + 8 * q);
#pragma unroll
                for (int t = 0; t < 8; ++t) acc[t] += bf2f(v[t]);
            }
        }
    }

    // reduce the 8 groups (lane bits 3,4,5)
#pragma unroll
    for (int mask = 8; mask <= 32; mask <<= 1) {
#pragma unroll
        for (int t = 0; t < 8; ++t) acc[t] += __shfl_xor(acc[t], mask);
    }

    if (g == 0 && qa) {
        ushort8v self = *(const ushort8v*)(XWs + (size_t)d * F + 8 * q);
        float dv = dinv[d];
        float o[8];
#pragma unroll
        for (int t = 0; t < 8; ++t) {
            o[t] = fmaf(acc[t] + bf2f(self[t]), dv, b[8 * q + t]);
            if (RELU) o[t] = fmaxf(o[t], 0.f);
        }
        float4 o0 = { o[0], o[1], o[2], o[3] };
        float4 o1 = { o[4], o[5], o[6], o[7] };
        *(float4*)(out + (size_t)d * F + 8 * q)     = o0;
        *(float4*)(out + (size_t)d * F + 8 * q + 4) = o1;
    }
}

extern "C" void kernel_launch(void* const* d_in, const int* in_sizes, int n_in,
                              void* d_out, int out_size, void* d_ws, size_t ws_size,
                              hipStream_t stream) {
    const float* x  = (const float*)d_in[0];
    const int*   ei = (const int*)d_in[1];
    const float* W1 = (const float*)d_in[2];
    const float* b1 = (const float*)d_in[3];
    const float* W2 = (const float*)d_in[4];
    const float* b2 = (const float*)d_in[5];
    const float* W3 = (const float*)d_in[6];
    const float* b3 = (const float*)d_in[7];
    float* out = (float*)d_out;

    const int* src = ei;
    const int* dst = ei + NEDGE;

    char* p = (char*)d_ws;
    auto alloc = [&](size_t bytes) { char* r = p; p += (bytes + 255) & ~size_t(255); return r; };
    unsigned int* bucketed = (unsigned int*)alloc((size_t)NEDGE * 4);
    int*   hist_g     = (int*)  alloc(NBUCKET * 256 * 4);
    int*   base_g     = (int*)  alloc(NBUCKET * 256 * 4);
    int*   colsum     = (int*)  alloc(NBUCKET * 4);
    int*   bucketbase = (int*)  alloc((NBUCKET + 1) * 4);
    int*   rowstart   = (int*)  alloc((NNODE + 1) * 4);
    int*   csr_src    = (int*)  alloc((size_t)NEDGE * 4);
    float* dinv       = (float*)alloc(NNODE * 4);
    unsigned short* XWs = (unsigned short*)alloc((size_t)NNODE * 64 * 2 + 256);  // bf16
    float* H1         = (float*)alloc((size_t)NNODE * 64 * 4);
    float* H2         = (float*)alloc((size_t)NNODE * 64 * 4);

    const int B = 256;
    const int gGemm = (NNODE + 63) / 64;          // 782 (64 rows/block)
    const int gAgg  = (NNODE + 3) / 4;            // 12500

    // CSR build + norm (deterministic-base counting sort)
    k_histA   <<<256, B, 0, stream>>>(dst, hist_g);
    k_scanA1  <<<NBUCKET, B, 0, stream>>>(hist_g, base_g, colsum);
    k_scanA2  <<<1, B, 0, stream>>>(colsum, bucketbase, rowstart);
    k_scatterA<<<256, B, 0, stream>>>(src, dst, base_g, bucketbase, bucketed);
    k_bucketB2<<<NBUCKET, B, 0, stream>>>(bucketed, bucketbase, rowstart, csr_src, dinv);

    // layer 1: 128 -> 64, relu
    k_gemm_prescale<128, 64><<<gGemm, B, 0, stream>>>(x, W1, dinv, XWs);
    k_aggregate<64, true><<<gAgg, B, 0, stream>>>(XWs, rowstart, csr_src, dinv, b1, H1);

    // layer 2: 64 -> 64, relu
    k_gemm_prescale<64, 64><<<gGemm, B, 0, stream>>>(H1, W2, dinv, XWs);
    k_aggregate<64, true><<<gAgg, B, 0, stream>>>(XWs, rowstart, csr_src, dinv, b2, H2);

    // layer 3: 64 -> 40, no act
    k_gemm_prescale<64, 40><<<gGemm, B, 0, stream>>>(H2, W3, dinv, XWs);
    k_aggregate<40, false><<<gAgg, B, 0, stream>>>(XWs, rowstart, csr_src, dinv, b3, out);
}

// Round 13
// 158.096 us; speedup vs baseline: 1.1395x; 1.0108x over previous
//
#include <hip/hip_runtime.h>

#define NNODE 50000
#define NEDGE 800000
#define NBUCKET 196         // ceil(50000 / 256), bucket = dst >> 8
#define NPB 256             // nodes per bucket
#define EPB 3125            // NEDGE / 256 edges per producer block

typedef __attribute__((ext_vector_type(8))) unsigned short ushort8v;

__device__ inline unsigned short f2bf(float f) {           // round-to-nearest-even
    unsigned int u = __float_as_uint(f);
    u += 0x7FFFu + ((u >> 16) & 1u);
    return (unsigned short)(u >> 16);
}
__device__ inline float bf2f(unsigned short h) {
    return __uint_as_float((unsigned int)h << 16);
}

// ---------------- Pass A: deterministic-base bucketize (bucket = dst>>8) ----

__global__ __launch_bounds__(256) void k_histA(const int* __restrict__ dst, int* __restrict__ hist_g) {
    __shared__ int h[NBUCKET];
    const int tid = threadIdx.x, pb = blockIdx.x, e0 = pb * EPB;
    if (tid < NBUCKET) h[tid] = 0;
    __syncthreads();
    for (int i = tid; i < EPB; i += 256)
        atomicAdd(&h[dst[e0 + i] >> 8], 1);
    __syncthreads();
    if (tid < NBUCKET) hist_g[tid * 256 + pb] = h[tid];
}

// per-bucket exclusive scan over producers; colsum[b] = bucket size
__global__ __launch_bounds__(256) void k_scanA1(const int* __restrict__ hist_g, int* __restrict__ base_g,
                                                int* __restrict__ colsum) {
    __shared__ int s[256];
    const int b = blockIdx.x, t = threadIdx.x;
    int v = hist_g[b * 256 + t];
    s[t] = v;
    __syncthreads();
#pragma unroll
    for (int off = 1; off < 256; off <<= 1) {
        int a = (t >= off) ? s[t - off] : 0;
        __syncthreads();
        s[t] += a;
        __syncthreads();
    }
    base_g[b * 256 + t] = s[t] - v;           // exclusive
    if (t == 255) colsum[b] = s[t];
}

// inclusive scan of colsum in LDS; returns cs (shared) filled
__device__ inline void scan_colsum(const int* __restrict__ colsum, int* cs, int tid) {
    cs[tid] = (tid < NBUCKET) ? colsum[tid] : 0;
    __syncthreads();
#pragma unroll
    for (int off = 1; off < 256; off <<= 1) {
        int a = (tid >= off) ? cs[tid - off] : 0;
        __syncthreads();
        cs[tid] += a;
        __syncthreads();
    }
}

__global__ __launch_bounds__(256) void k_scatterA(const int* __restrict__ src, const int* __restrict__ dst,
                          const int* __restrict__ base_g, const int* __restrict__ colsum,
                          unsigned int* __restrict__ bucketed) {
    __shared__ int cs[256];
    __shared__ int cur[NBUCKET];
    const int tid = threadIdx.x, pb = blockIdx.x, e0 = pb * EPB;
    scan_colsum(colsum, cs, tid);
    if (tid < NBUCKET) {
        int bb = (tid == 0) ? 0 : cs[tid - 1];       // exclusive bucket base
        cur[tid] = bb + base_g[tid * 256 + pb];
    }
    __syncthreads();
    for (int i = tid; i < EPB; i += 256) {
        int d = dst[e0 + i], s = src[e0 + i];
        int pos = atomicAdd(&cur[d >> 8], 1);
        bucketed[pos] = ((unsigned int)d << 16) | (unsigned int)s;
    }
}

// ---------------- Pass B: per-bucket fine CSR (contiguous reads) ----------

__global__ __launch_bounds__(256) void k_bucketB2(const unsigned int* __restrict__ bucketed,
                          const int* __restrict__ colsum, int* __restrict__ rowstart,
                          unsigned short* __restrict__ csr_src, float* __restrict__ dinv) {
    __shared__ int cs[256];
    __shared__ int cnt[NPB];
    __shared__ int ex[NPB];
    __shared__ int cur[NPB];
    const int tid = threadIdx.x, b = blockIdx.x;
    scan_colsum(colsum, cs, tid);
    const int base_out = (b == 0) ? 0 : cs[b - 1];
    const int end_out  = cs[b];

    cnt[tid] = 0;
    __syncthreads();
    for (int i = base_out + tid; i < end_out; i += 256)
        atomicAdd(&cnt[(bucketed[i] >> 16) & 255], 1);
    __syncthreads();

    int v = cnt[tid];
    ex[tid] = v;
    __syncthreads();
#pragma unroll
    for (int off = 1; off < 256; off <<= 1) {
        int a = (tid >= off) ? ex[tid - off] : 0;
        __syncthreads();
        ex[tid] += a;
        __syncthreads();
    }
    int excl = ex[tid] - v;
    int node = (b << 8) + tid;
    cur[tid] = base_out + excl;
    if (node < NNODE) {
        rowstart[node] = base_out + excl;
        dinv[node] = rsqrtf((float)v + 1.0f);
    }
    if (b == 0 && tid == 0) rowstart[NNODE] = NEDGE;
    __syncthreads();

    for (int i = base_out + tid; i < end_out; i += 256) {
        unsigned int u = bucketed[i];
        int pos = atomicAdd(&cur[(u >> 16) & 255], 1);
        csr_src[pos] = (unsigned short)(u & 0xFFFFu);
    }
}

// ---------------- GEMM + prescale: 64x64 LDS tile, bf16 out, f32/bf16 in ----

template<int FIN, int FOUT, typename XT>
__launch_bounds__(256)
__global__ void k_gemm_prescale(const XT* __restrict__ X, const float* __restrict__ W,
                                const float* __restrict__ dinv, unsigned short* __restrict__ XWs) {
    __shared__ float Xt[FIN * 68];
    __shared__ float Ws[FIN * 64];

    const int tid = threadIdx.x;
    const int r0 = blockIdx.x * 64;

    for (int idx = tid; idx < FIN * 64; idx += 256) {
        int k = idx >> 6, c = idx & 63;
        Ws[idx] = (c < FOUT) ? W[k * FOUT + c] : 0.0f;
    }

    if constexpr (sizeof(XT) == 4) {       // f32 input, float4 chunks
        constexpr int CH = FIN / 4;
        constexpr int CSH = (FIN == 128) ? 5 : 4;
        for (int idx = tid; idx < 64 * CH; idx += 256) {
            int r_lo = idx & 7;
            int c = (idx >> 3) & (CH - 1);
            int r = ((idx >> (3 + CSH)) << 3) + r_lo;
            int rr = r0 + r; if (rr >= NNODE) rr = NNODE - 1;
            float4 v = *(const float4*)((const float*)X + (size_t)rr * FIN + c * 4);
            Xt[(4 * c + 0) * 68 + r] = v.x;
            Xt[(4 * c + 1) * 68 + r] = v.y;
            Xt[(4 * c + 2) * 68 + r] = v.z;
            Xt[(4 * c + 3) * 68 + r] = v.w;
        }
    } else {                               // bf16 input, ushort8 chunks
        constexpr int CH = FIN / 8;
        constexpr int CSH = (FIN == 128) ? 4 : 3;
        for (int idx = tid; idx < 64 * CH; idx += 256) {
            int r_lo = idx & 7;
            int c = (idx >> 3) & (CH - 1);
            int r = ((idx >> (3 + CSH)) << 3) + r_lo;
            int rr = r0 + r; if (rr >= NNODE) rr = NNODE - 1;
            ushort8v v = *(const ushort8v*)((const unsigned short*)X + (size_t)rr * FIN + c * 8);
#pragma unroll
            for (int t = 0; t < 8; ++t)
                Xt[(8 * c + t) * 68 + r] = bf2f(v[t]);
        }
    }
    __syncthreads();

    const int cg = tid & 15;    // col group
    const int rg = tid >> 4;    // row group

    float acc[4][4] = {};
#pragma unroll 4
    for (int k = 0; k < FIN; ++k) {
        float4 xv = *(const float4*)&Xt[k * 68 + 4 * rg];
        float4 wv = *(const float4*)&Ws[k * 64 + 4 * cg];
#pragma unroll
        for (int i = 0; i < 4; ++i) {
            float xi = (i == 0) ? xv.x : (i == 1) ? xv.y : (i == 2) ? xv.z : xv.w;
            acc[i][0] = fmaf(xi, wv.x, acc[i][0]);
            acc[i][1] = fmaf(xi, wv.y, acc[i][1]);
            acc[i][2] = fmaf(xi, wv.z, acc[i][2]);
            acc[i][3] = fmaf(xi, wv.w, acc[i][3]);
        }
    }

    if (4 * cg + 4 <= FOUT) {
#pragma unroll
        for (int i = 0; i < 4; ++i) {
            int row = r0 + 4 * rg + i;
            if (row < NNODE) {
                float dv = dinv[row];
                ushort4 o = { f2bf(acc[i][0] * dv), f2bf(acc[i][1] * dv),
                              f2bf(acc[i][2] * dv), f2bf(acc[i][3] * dv) };
                *(ushort4*)(XWs + (size_t)row * FOUT + 4 * cg) = o;
            }
        }
    }
}

// ---------------- CSR aggregate + finalize: 8-edge bf16 ushort8 groups -----
// wave per node; lane = g*8+q (g = edge group 0..7, q = feature octet).
// OUTBF: write bf16 (inter-layer) else f32 (final output).

template<int F, bool RELU, bool OUTBF>
__launch_bounds__(256)
__global__ void k_aggregate(const unsigned short* __restrict__ XWs, const int* __restrict__ rowstart,
                            const unsigned short* __restrict__ csr_src, const float* __restrict__ dinv,
                            const float* __restrict__ b, void* __restrict__ outp) {
    constexpr int NQ = F / 8;           // 8 for F=64, 5 for F=40
    const int wid  = threadIdx.x >> 6;
    const int lane = threadIdx.x & 63;
    const int g = lane >> 3;            // edge group 0..7
    const int q = lane & 7;             // feature octet
    const int d = blockIdx.x * 4 + wid;
    if (d >= NNODE) return;

    const int beg = rowstart[d];
    const int end = rowstart[d + 1];
    const bool qa = (q < NQ);

    float acc[8] = {};

    for (int base = beg; base < end; base += 64) {
        int idx = base + lane;
        int sv = (idx < end) ? (int)csr_src[idx] : 0;   // coalesced 2B edge load
        int nv = min(64, end - base);
        for (int j = 0; j < nv; j += 8) {
            int jj = j + g;
            int s = __shfl(sv, jj);
            if (jj < nv && qa) {
                ushort8v v = *(const ushort8v*)(XWs + (size_t)s * F + 8 * q);
#pragma unroll
                for (int t = 0; t < 8; ++t) acc[t] += bf2f(v[t]);
            }
        }
    }

    // reduce the 8 groups (lane bits 3,4,5)
#pragma unroll
    for (int mask = 8; mask <= 32; mask <<= 1) {
#pragma unroll
        for (int t = 0; t < 8; ++t) acc[t] += __shfl_xor(acc[t], mask);
    }

    if (g == 0 && qa) {
        ushort8v self = *(const ushort8v*)(XWs + (size_t)d * F + 8 * q);
        float dv = dinv[d];
        float o[8];
#pragma unroll
        for (int t = 0; t < 8; ++t) {
            o[t] = fmaf(acc[t] + bf2f(self[t]), dv, b[8 * q + t]);
            if (RELU) o[t] = fmaxf(o[t], 0.f);
        }
        if (OUTBF) {
            ushort8v ov;
#pragma unroll
            for (int t = 0; t < 8; ++t) ov[t] = f2bf(o[t]);
            *(ushort8v*)((unsigned short*)outp + (size_t)d * F + 8 * q) = ov;
        } else {
            float4 o0 = { o[0], o[1], o[2], o[3] };
            float4 o1 = { o[4], o[5], o[6], o[7] };
            *(float4*)((float*)outp + (size_t)d * F + 8 * q)     = o0;
            *(float4*)((float*)outp + (size_t)d * F + 8 * q + 4) = o1;
        }
    }
}

extern "C" void kernel_launch(void* const* d_in, const int* in_sizes, int n_in,
                              void* d_out, int out_size, void* d_ws, size_t ws_size,
                              hipStream_t stream) {
    const float* x  = (const float*)d_in[0];
    const int*   ei = (const int*)d_in[1];
    const float* W1 = (const float*)d_in[2];
    const float* b1 = (const float*)d_in[3];
    const float* W2 = (const float*)d_in[4];
    const float* b2 = (const float*)d_in[5];
    const float* W3 = (const float*)d_in[6];
    const float* b3 = (const float*)d_in[7];
    float* out = (float*)d_out;

    const int* src = ei;
    const int* dst = ei + NEDGE;

    char* p = (char*)d_ws;
    auto alloc = [&](size_t bytes) { char* r = p; p += (bytes + 255) & ~size_t(255); return r; };
    unsigned int* bucketed = (unsigned int*)alloc((size_t)NEDGE * 4);
    int*   hist_g     = (int*)  alloc(NBUCKET * 256 * 4);
    int*   base_g     = (int*)  alloc(NBUCKET * 256 * 4);
    int*   colsum     = (int*)  alloc(NBUCKET * 4);
    int*   rowstart   = (int*)  alloc((NNODE + 1) * 4);
    unsigned short* csr_src = (unsigned short*)alloc((size_t)NEDGE * 2);
    float* dinv       = (float*)alloc(NNODE * 4);
    unsigned short* XWs = (unsigned short*)alloc((size_t)NNODE * 64 * 2 + 256);  // bf16
    unsigned short* H1  = (unsigned short*)alloc((size_t)NNODE * 64 * 2 + 256);  // bf16
    unsigned short* H2  = (unsigned short*)alloc((size_t)NNODE * 64 * 2 + 256);  // bf16

    const int B = 256;
    const int gGemm = (NNODE + 63) / 64;          // 782 (64 rows/block)
    const int gAgg  = (NNODE + 3) / 4;            // 12500

    // CSR build + norm (deterministic-base counting sort; colsum scans inlined)
    k_histA   <<<256, B, 0, stream>>>(dst, hist_g);
    k_scanA1  <<<NBUCKET, B, 0, stream>>>(hist_g, base_g, colsum);
    k_scatterA<<<256, B, 0, stream>>>(src, dst, base_g, colsum, bucketed);
    k_bucketB2<<<NBUCKET, B, 0, stream>>>(bucketed, colsum, rowstart, csr_src, dinv);

    // layer 1: 128 -> 64, relu (f32 input)
    k_gemm_prescale<128, 64, float><<<gGemm, B, 0, stream>>>(x, W1, dinv, XWs);
    k_aggregate<64, true, true><<<gAgg, B, 0, stream>>>(XWs, rowstart, csr_src, dinv, b1, H1);

    // layer 2: 64 -> 64, relu (bf16 input)
    k_gemm_prescale<64, 64, unsigned short><<<gGemm, B, 0, stream>>>(H1, W2, dinv, XWs);
    k_aggregate<64, true, true><<<gAgg, B, 0, stream>>>(XWs, rowstart, csr_src, dinv, b2, H2);

    // layer 3: 64 -> 40, no act (bf16 input, f32 output)
    k_gemm_prescale<64, 40, unsigned short><<<gGemm, B, 0, stream>>>(H2, W3, dinv, XWs);
    k_aggregate<40, false, false><<<gAgg, B, 0, stream>>>(XWs, rowstart, csr_src, dinv, b3, out);
}